// Round 1
// baseline (1156.124 us; speedup 1.0000x reference)
//
#include <hip/hip_runtime.h>
#include <math.h>

#define HDIM 64
#define GN_EPS 1e-5f

__device__ __forceinline__ int lower_bound_i(const int* a, int n, int key){
  int lo = 0, hi = n;
  while (lo < hi){ int mid = (lo + hi) >> 1; if (a[mid] < key) lo = mid + 1; else hi = mid; }
  return lo;
}

// ---------------- CSR build ----------------
__global__ void k_deg(const int* __restrict__ dst, int* __restrict__ deg, int E){
  int i = blockIdx.x * blockDim.x + threadIdx.x;
  if (i < E) atomicAdd(&deg[dst[i]], 1);
}

__global__ void k_scan1(const int* __restrict__ deg, int* __restrict__ offs,
                        int* __restrict__ part, int n){
  __shared__ int sd[256];
  int tid = threadIdx.x;
  int base = blockIdx.x * 1024 + tid * 4;
  int v0 = (base + 0 < n) ? deg[base + 0] : 0;
  int v1 = (base + 1 < n) ? deg[base + 1] : 0;
  int v2 = (base + 2 < n) ? deg[base + 2] : 0;
  int v3 = (base + 3 < n) ? deg[base + 3] : 0;
  int L = v0 + v1 + v2 + v3;
  sd[tid] = L; __syncthreads();
  for (int o = 1; o < 256; o <<= 1){
    int t = (tid >= o) ? sd[tid - o] : 0;
    __syncthreads();
    sd[tid] += t;
    __syncthreads();
  }
  int run = sd[tid] - L;   // exclusive prefix for this thread
  if (base + 0 < n) offs[base + 0] = run; run += v0;
  if (base + 1 < n) offs[base + 1] = run; run += v1;
  if (base + 2 < n) offs[base + 2] = run; run += v2;
  if (base + 3 < n) offs[base + 3] = run;
  if (tid == 255) part[blockIdx.x] = sd[255];
}

__global__ void k_scan2(int* part, int nb){
  __shared__ int sd[256];
  int tid = threadIdx.x;
  int v = (tid < nb) ? part[tid] : 0;
  sd[tid] = v; __syncthreads();
  for (int o = 1; o < 256; o <<= 1){
    int t = (tid >= o) ? sd[tid - o] : 0;
    __syncthreads();
    sd[tid] += t;
    __syncthreads();
  }
  if (tid < nb) part[tid] = sd[tid] - v;  // exclusive
}

__global__ void k_scan3(int* __restrict__ offs, int* __restrict__ cursor,
                        const int* __restrict__ part, int n){
  int i = blockIdx.x * blockDim.x + threadIdx.x;
  if (i < n){ int o = offs[i] + part[i >> 10]; offs[i] = o; cursor[i] = o; }
}

__global__ void k_scatter(const int* __restrict__ src, const int* __restrict__ dst,
                          int* __restrict__ cursor, int* __restrict__ csr, int E){
  int i = blockIdx.x * blockDim.x + threadIdx.x;
  if (i < E){ int d = dst[i]; int pos = atomicAdd(&cursor[d], 1); csr[pos] = src[i]; }
}

// ---------------- GIN aggregation: G[n] = P[n] + sum_{e->n} P[src] ----------------
__global__ void k_agg(const float* __restrict__ P, const int* __restrict__ csr,
                      const int* __restrict__ offs, const int* __restrict__ deg,
                      float* __restrict__ G, int n){
  int gi = blockIdx.x * blockDim.x + threadIdx.x;
  int node = gi >> 6;
  int lane = gi & 63;
  if (node >= n) return;
  int st = offs[node], cnt = deg[node];
  float acc = P[(size_t)node * HDIM + lane];
  float a0 = 0.f, a1 = 0.f, a2 = 0.f, a3 = 0.f;
  int j = 0;
  for (; j + 4 <= cnt; j += 4){
    int s0 = csr[st + j], s1 = csr[st + j + 1], s2 = csr[st + j + 2], s3 = csr[st + j + 3];
    a0 += P[(size_t)s0 * HDIM + lane];
    a1 += P[(size_t)s1 * HDIM + lane];
    a2 += P[(size_t)s2 * HDIM + lane];
    a3 += P[(size_t)s3 * HDIM + lane];
  }
  for (; j < cnt; ++j){ int s = csr[st + j]; a0 += P[(size_t)s * HDIM + lane]; }
  G[(size_t)node * HDIM + lane] = acc + ((a0 + a1) + (a2 + a3));
}

// ---------------- GIN MLP: G[n] = relu(G[n] @ W1 + B1) @ W2 + B2 (in place) -------
__global__ __launch_bounds__(128, 2) void k_mlp(float* __restrict__ G,
    const float* __restrict__ W1, const float* __restrict__ B1,
    const float* __restrict__ W2, const float* __restrict__ B2, int n){
  __shared__ float lt[64 * 128];   // 32 KiB: relu(t) transposed, stride 128 (2-way bank = free)
  int tid = threadIdx.x;
  int node = blockIdx.x * 128 + tid;
  bool ok = node < n;
  const float4* hp = (const float4*)(G + (ok ? (size_t)node * HDIM : 0));

  float t[64];
  #pragma unroll
  for (int j = 0; j < 64; j++) t[j] = B1[j];
  for (int ii = 0; ii < 4; ++ii){          // not unrolled: keeps code small, W row uniform
    float4 c0 = hp[ii * 4 + 0], c1 = hp[ii * 4 + 1], c2 = hp[ii * 4 + 2], c3 = hp[ii * 4 + 3];
    float hc[16] = {c0.x, c0.y, c0.z, c0.w, c1.x, c1.y, c1.z, c1.w,
                    c2.x, c2.y, c2.z, c2.w, c3.x, c3.y, c3.z, c3.w};
    const float* wrow = W1 + (size_t)ii * 16 * 64;
    #pragma unroll
    for (int k = 0; k < 16; k++){
      float hv = hc[k];
      #pragma unroll
      for (int j = 0; j < 64; j++) t[j] += hv * wrow[k * 64 + j];
    }
  }
  #pragma unroll
  for (int j = 0; j < 64; j++) lt[j * 128 + tid] = fmaxf(t[j], 0.f);
  // each thread reads back only its own column -> no __syncthreads needed

  float o[64];
  #pragma unroll
  for (int j = 0; j < 64; j++) o[j] = B2[j];
  for (int ii = 0; ii < 4; ++ii){
    const float* wrow = W2 + (size_t)ii * 16 * 64;
    #pragma unroll
    for (int k = 0; k < 16; k++){
      float tv = lt[(ii * 16 + k) * 128 + tid];
      #pragma unroll
      for (int j = 0; j < 64; j++) o[j] += tv * wrow[k * 64 + j];
    }
  }
  if (ok){
    float4* op = (float4*)(G + (size_t)node * HDIM);
    #pragma unroll
    for (int q = 0; q < 16; q++) op[q] = make_float4(o[q*4], o[q*4+1], o[q*4+2], o[q*4+3]);
  }
}

// ---------------- GraphNorm + ReLU + residual accumulate ----------------
__global__ void k_gn(const float* __restrict__ Y, const int* __restrict__ batch, int nnode,
                     const float* __restrict__ w, const float* __restrict__ b,
                     const float* __restrict__ ms,
                     float* __restrict__ C, float* __restrict__ hsum){
  __shared__ float part[4][64];
  __shared__ float meanv[64];
  __shared__ float scalev[64];
  int g = blockIdx.x;
  int tid = threadIdx.x;
  int f = tid & 63, r = tid >> 6;
  int start = lower_bound_i(batch, nnode, g);
  int end   = lower_bound_i(batch, nnode, g + 1);
  float cntf = (float)max(end - start, 1);

  float s = 0.f;
  for (int nd = start + r; nd < end; nd += 4) s += Y[(size_t)nd * HDIM + f];
  part[r][f] = s; __syncthreads();
  if (r == 0){
    float m = (part[0][f] + part[1][f] + part[2][f] + part[3][f]) / cntf;
    meanv[f] = ms[f] * m;
  }
  __syncthreads();
  float msm = meanv[f];
  float s2 = 0.f;
  for (int nd = start + r; nd < end; nd += 4){
    float o = Y[(size_t)nd * HDIM + f] - msm; s2 += o * o;
  }
  part[r][f] = s2; __syncthreads();
  if (r == 0){
    float var = (part[0][f] + part[1][f] + part[2][f] + part[3][f]) / cntf;
    scalev[f] = rsqrtf(var + GN_EPS) * w[f];
  }
  __syncthreads();
  float sc = scalev[f], bb = b[f];
  for (int nd = start + r; nd < end; nd += 4){
    size_t idx = (size_t)nd * HDIM + f;
    float o = Y[idx] - msm;
    float v = fmaxf(o * sc + bb, 0.f);
    C[idx] = v;
    hsum[idx] += v;
  }
}

// ---------------- pooling (attention + mean + max) + head MLP ----------------
__global__ void k_pool(const float* __restrict__ HS, const int* __restrict__ batch, int nnode,
                       const float* __restrict__ GW, const float* __restrict__ GB,
                       const float* __restrict__ U,
                       const float* __restrict__ HW1, const float* __restrict__ HB1,
                       const float* __restrict__ HW2, const float* __restrict__ HB2,
                       float* __restrict__ gatebuf, float* __restrict__ out){
  __shared__ float meanp[4][64], maxp[4][64], attp[4][64];
  __shared__ float denp[4], gmaxp[4];
  __shared__ float z[256];
  __shared__ float mval;
  int g = blockIdx.x;
  int tid = threadIdx.x;
  int lane = tid & 63, r = tid >> 6;
  int start = lower_bound_i(batch, nnode, g);
  int end   = lower_bound_i(batch, nnode, g + 1);
  float cntf = (float)max(end - start, 1);
  float gwv = GW[lane];

  float macc = 0.f, xacc = -INFINITY, gmax = -INFINITY;
  for (int nd = start + r; nd < end; nd += 4){
    float hv = HS[(size_t)nd * HDIM + lane];
    macc += hv; xacc = fmaxf(xacc, hv);
    float gv = hv * gwv;
    #pragma unroll
    for (int msk = 1; msk < 64; msk <<= 1) gv += __shfl_xor(gv, msk);
    gv += GB[0];
    if (lane == 0) gatebuf[nd] = gv;
    gmax = fmaxf(gmax, gv);
  }
  meanp[r][lane] = macc; maxp[r][lane] = xacc;
  if (lane == 0) gmaxp[r] = gmax;
  __syncthreads();
  if (tid == 0) mval = fmaxf(fmaxf(gmaxp[0], gmaxp[1]), fmaxf(gmaxp[2], gmaxp[3]));
  __syncthreads();
  float m = mval;

  float dacc = 0.f, aacc = 0.f;
  for (int nd = start + r; nd < end; nd += 4){
    float ex = expf(gatebuf[nd] - m);
    float hv = HS[(size_t)nd * HDIM + lane];
    dacc += ex; aacc += ex * hv;
  }
  attp[r][lane] = aacc; if (lane == 0) denp[r] = dacc;
  __syncthreads();

  if (tid < 64){
    int f = tid;
    float den = denp[0] + denp[1] + denp[2] + denp[3];
    float att = (attp[0][f] + attp[1][f] + attp[2][f] + attp[3][f]) / den;
    float mn  = (meanp[0][f] + meanp[1][f] + meanp[2][f] + meanp[3][f]) / cntf;
    float mx  = fmaxf(fmaxf(maxp[0][f], maxp[1][f]), fmaxf(maxp[2][f], maxp[3][f]));
    z[f] = att; z[64 + f] = mn; z[128 + f] = mx;
  }
  if (tid < 3) z[192 + tid] = U[g * 3 + tid];
  __syncthreads();

  if (tid < 64){
    float acc = HB1[tid];
    for (int k = 0; k < 195; k++) acc += z[k] * HW1[k * 64 + tid];
    float sv = fmaxf(acc, 0.f) * HW2[tid];
    #pragma unroll
    for (int msk = 1; msk < 64; msk <<= 1) sv += __shfl_xor(sv, msk);
    if (tid == 0) out[g] = sv + HB2[0];
  }
}

extern "C" void kernel_launch(void* const* d_in, const int* in_sizes, int n_in,
                              void* d_out, int out_size, void* d_ws, size_t ws_size,
                              hipStream_t stream){
  const float* x     = (const float*)d_in[0];
  const int*   ei    = (const int*)d_in[1];
  const int*   batch = (const int*)d_in[2];
  const float* u     = (const float*)d_in[3];
  const float* W[3][4]; const float* GNp[3][3];
  for (int l = 0; l < 3; l++){
    int base = 4 + l * 7;
    W[l][0]  = (const float*)d_in[base + 0];
    W[l][1]  = (const float*)d_in[base + 1];
    W[l][2]  = (const float*)d_in[base + 2];
    W[l][3]  = (const float*)d_in[base + 3];
    GNp[l][0]= (const float*)d_in[base + 4];
    GNp[l][1]= (const float*)d_in[base + 5];
    GNp[l][2]= (const float*)d_in[base + 6];
  }
  const float* gate_w = (const float*)d_in[25];
  const float* gate_b = (const float*)d_in[26];
  const float* hw1    = (const float*)d_in[27];
  const float* hb1    = (const float*)d_in[28];
  const float* hw2    = (const float*)d_in[29];
  const float* hb2    = (const float*)d_in[30];
  float* out = (float*)d_out;

  int N = in_sizes[0] / HDIM;
  int E = in_sizes[1] / 2;
  int B = in_sizes[3] / 3;
  const int* src = ei;
  const int* dst = ei + E;

  char* w8 = (char*)d_ws;
  size_t NH = (size_t)N * HDIM * sizeof(float);
  auto alignup = [](size_t v){ return (v + 255) & ~(size_t)255; };
  size_t off = 0;
  float* hsum    = (float*)(w8 + off); off += alignup(NH);
  float* bufA    = (float*)(w8 + off); off += alignup(NH);
  float* bufB    = (float*)(w8 + off); off += alignup(NH);
  float* G       = (float*)(w8 + off); off += alignup(NH);
  float* gatebuf = (float*)(w8 + off); off += alignup((size_t)N * 4);
  int*   deg     = (int*)(w8 + off);   off += alignup((size_t)N * 4);
  int*   offs    = (int*)(w8 + off);   off += alignup((size_t)N * 4);
  int*   cursor  = (int*)(w8 + off);   off += alignup((size_t)N * 4);
  int*   part    = (int*)(w8 + off);   off += alignup(4096);
  int*   csr     = (int*)(w8 + off);   off += alignup((size_t)E * 4);
  (void)ws_size; (void)n_in; (void)out_size;

  hipMemsetAsync(deg, 0, (size_t)N * 4, stream);
  hipMemsetAsync(hsum, 0, NH, stream);

  const int tb = 256;
  k_deg<<<(E + tb - 1) / tb, tb, 0, stream>>>(dst, deg, E);
  int nchunk = (N + 1023) / 1024;
  k_scan1<<<nchunk, 256, 0, stream>>>(deg, offs, part, N);
  k_scan2<<<1, 256, 0, stream>>>(part, nchunk);
  k_scan3<<<(N + 255) / 256, 256, 0, stream>>>(offs, cursor, part, N);
  k_scatter<<<(E + tb - 1) / tb, tb, 0, stream>>>(src, dst, cursor, csr, E);

  const float* P = x;
  float* C = bufA;
  for (int l = 0; l < 3; l++){
    unsigned aggblocks = (unsigned)(((size_t)N * HDIM + 255) / 256);
    k_agg<<<aggblocks, 256, 0, stream>>>(P, csr, offs, deg, G, N);
    k_mlp<<<(N + 127) / 128, 128, 0, stream>>>(G, W[l][0], W[l][1], W[l][2], W[l][3], N);
    k_gn<<<B, 256, 0, stream>>>(G, batch, N, GNp[l][0], GNp[l][1], GNp[l][2], C, hsum);
    P = C;
    C = (l == 0) ? bufB : bufA;
  }
  k_pool<<<B, 256, 0, stream>>>(hsum, batch, N, gate_w, gate_b, u,
                                hw1, hb1, hw2, hb2, gatebuf, out);
}

// Round 2
// 741.280 us; speedup vs baseline: 1.5596x; 1.5596x over previous
//
#include <hip/hip_runtime.h>
#include <math.h>

#define HDIM 64
#define GN_EPS 1e-5f

__device__ __forceinline__ int lower_bound_i(const int* a, int n, int key){
  int lo = 0, hi = n;
  while (lo < hi){ int mid = (lo + hi) >> 1; if (a[mid] < key) lo = mid + 1; else hi = mid; }
  return lo;
}

// ordered-uint encoding for float atomicMax (monotonic: enc(a)<enc(b) <=> a<b)
__device__ __forceinline__ unsigned fenc(float x){
  unsigned b = __float_as_uint(x);
  return (b & 0x80000000u) ? ~b : (b | 0x80000000u);
}
__device__ __forceinline__ float fdec(unsigned u){
  unsigned b = (u & 0x80000000u) ? (u ^ 0x80000000u) : ~u;
  return __uint_as_float(b);
}

// ---------------- CSR build ----------------
__global__ void k_deg(const int* __restrict__ dst, int* __restrict__ deg, int E){
  int i = blockIdx.x * blockDim.x + threadIdx.x;
  if (i < E) atomicAdd(&deg[dst[i]], 1);
}

__global__ void k_scan1(const int* __restrict__ deg, int* __restrict__ offs,
                        int* __restrict__ part, int n){
  __shared__ int sd[256];
  int tid = threadIdx.x;
  int base = blockIdx.x * 1024 + tid * 4;
  int v0 = (base + 0 < n) ? deg[base + 0] : 0;
  int v1 = (base + 1 < n) ? deg[base + 1] : 0;
  int v2 = (base + 2 < n) ? deg[base + 2] : 0;
  int v3 = (base + 3 < n) ? deg[base + 3] : 0;
  int L = v0 + v1 + v2 + v3;
  sd[tid] = L; __syncthreads();
  for (int o = 1; o < 256; o <<= 1){
    int t = (tid >= o) ? sd[tid - o] : 0;
    __syncthreads();
    sd[tid] += t;
    __syncthreads();
  }
  int run = sd[tid] - L;
  if (base + 0 < n) offs[base + 0] = run; run += v0;
  if (base + 1 < n) offs[base + 1] = run; run += v1;
  if (base + 2 < n) offs[base + 2] = run; run += v2;
  if (base + 3 < n) offs[base + 3] = run;
  if (tid == 255) part[blockIdx.x] = sd[255];
}

__global__ void k_scan2(int* part, int nb){
  __shared__ int sd[256];
  int tid = threadIdx.x;
  int v = (tid < nb) ? part[tid] : 0;
  sd[tid] = v; __syncthreads();
  for (int o = 1; o < 256; o <<= 1){
    int t = (tid >= o) ? sd[tid - o] : 0;
    __syncthreads();
    sd[tid] += t;
    __syncthreads();
  }
  if (tid < nb) part[tid] = sd[tid] - v;
}

__global__ void k_scan3(int* __restrict__ offs, int* __restrict__ cursor,
                        const int* __restrict__ part, int n){
  int i = blockIdx.x * blockDim.x + threadIdx.x;
  if (i < n){ int o = offs[i] + part[i >> 10]; offs[i] = o; cursor[i] = o; }
}

__global__ void k_scatter(const int* __restrict__ src, const int* __restrict__ dst,
                          int* __restrict__ cursor, int* __restrict__ csr, int E){
  int i = blockIdx.x * blockDim.x + threadIdx.x;
  if (i < E){ int d = dst[i]; int pos = atomicAdd(&cursor[d], 1); csr[pos] = src[i]; }
}

// graph start offsets (batch is sorted)
__global__ void k_gstart(const int* __restrict__ batch, int n, int* __restrict__ gs, int B){
  int g = blockIdx.x * blockDim.x + threadIdx.x;
  if (g <= B) gs[g] = lower_bound_i(batch, n, g);
}

// ---------------- GIN aggregation: G[n] = P[n] + sum_{e->n} P[src] ----------------
__global__ void k_agg(const float* __restrict__ P, const int* __restrict__ csr,
                      const int* __restrict__ offs, const int* __restrict__ deg,
                      float* __restrict__ G, int n){
  int gi = blockIdx.x * blockDim.x + threadIdx.x;
  int node = gi >> 6;
  int lane = gi & 63;
  if (node >= n) return;
  int st = offs[node], cnt = deg[node];
  float acc = P[(size_t)node * HDIM + lane];
  float a0 = 0.f, a1 = 0.f, a2 = 0.f, a3 = 0.f;
  int j = 0;
  for (; j + 4 <= cnt; j += 4){
    int s0 = csr[st + j], s1 = csr[st + j + 1], s2 = csr[st + j + 2], s3 = csr[st + j + 3];
    a0 += P[(size_t)s0 * HDIM + lane];
    a1 += P[(size_t)s1 * HDIM + lane];
    a2 += P[(size_t)s2 * HDIM + lane];
    a3 += P[(size_t)s3 * HDIM + lane];
  }
  for (; j < cnt; ++j){ int s = csr[st + j]; a0 += P[(size_t)s * HDIM + lane]; }
  G[(size_t)node * HDIM + lane] = acc + ((a0 + a1) + (a2 + a3));
}

// ---------------- GIN MLP: G[n] = relu(G[n] @ W1 + B1) @ W2 + B2 (in place) -------
__global__ __launch_bounds__(128, 2) void k_mlp(float* __restrict__ G,
    const float* __restrict__ W1, const float* __restrict__ B1,
    const float* __restrict__ W2, const float* __restrict__ B2, int n){
  __shared__ float lt[64 * 128];
  int tid = threadIdx.x;
  int node = blockIdx.x * 128 + tid;
  bool ok = node < n;
  const float4* hp = (const float4*)(G + (ok ? (size_t)node * HDIM : 0));

  float t[64];
  #pragma unroll
  for (int j = 0; j < 64; j++) t[j] = B1[j];
  for (int ii = 0; ii < 4; ++ii){
    float4 c0 = hp[ii * 4 + 0], c1 = hp[ii * 4 + 1], c2 = hp[ii * 4 + 2], c3 = hp[ii * 4 + 3];
    float hc[16] = {c0.x, c0.y, c0.z, c0.w, c1.x, c1.y, c1.z, c1.w,
                    c2.x, c2.y, c2.z, c2.w, c3.x, c3.y, c3.z, c3.w};
    const float* wrow = W1 + (size_t)ii * 16 * 64;
    #pragma unroll
    for (int k = 0; k < 16; k++){
      float hv = hc[k];
      #pragma unroll
      for (int j = 0; j < 64; j++) t[j] += hv * wrow[k * 64 + j];
    }
  }
  #pragma unroll
  for (int j = 0; j < 64; j++) lt[j * 128 + tid] = fmaxf(t[j], 0.f);

  float o[64];
  #pragma unroll
  for (int j = 0; j < 64; j++) o[j] = B2[j];
  for (int ii = 0; ii < 4; ++ii){
    const float* wrow = W2 + (size_t)ii * 16 * 64;
    #pragma unroll
    for (int k = 0; k < 16; k++){
      float tv = lt[(ii * 16 + k) * 128 + tid];
      #pragma unroll
      for (int j = 0; j < 64; j++) o[j] += tv * wrow[k * 64 + j];
    }
  }
  if (ok){
    float4* op = (float4*)(G + (size_t)node * HDIM);
    #pragma unroll
    for (int q = 0; q < 16; q++) op[q] = make_float4(o[q*4], o[q*4+1], o[q*4+2], o[q*4+3]);
  }
}

// ---------------- GraphNorm, phase A: per-graph sum / sumsq (chunked-flush) -------
#define GN_NPW 32
__global__ void k_gn_stats(const float* __restrict__ Y, const int* __restrict__ batch,
                           float* __restrict__ stats /*[B][2][64]*/, int n){
  int wave = (int)((blockIdx.x * blockDim.x + threadIdx.x) >> 6);
  int lane = threadIdx.x & 63;
  int s = wave * GN_NPW;
  if (s >= n) return;
  int e = min(s + GN_NPW, n);
  int cur = batch[s];
  float a = 0.f, a2 = 0.f;
  for (int nd = s; nd < e; ++nd){
    int g = batch[nd];
    if (g != cur){
      atomicAdd(&stats[cur * 128 + lane], a);
      atomicAdd(&stats[cur * 128 + 64 + lane], a2);
      a = 0.f; a2 = 0.f; cur = g;
    }
    float v = Y[(size_t)nd * HDIM + lane];
    a += v; a2 += v * v;
  }
  atomicAdd(&stats[cur * 128 + lane], a);
  atomicAdd(&stats[cur * 128 + 64 + lane], a2);
}

// ---------------- GraphNorm, phase B: finalize mean*ms and scale ----------------
__global__ void k_gn_finalize(const float* __restrict__ stats, const int* __restrict__ gs,
                              const float* __restrict__ w, const float* __restrict__ ms,
                              float* __restrict__ meanms, float* __restrict__ scale, int B){
  int i = blockIdx.x * blockDim.x + threadIdx.x;
  if (i >= B * 64) return;
  int g = i >> 6, f = i & 63;
  float cnt = (float)max(gs[g + 1] - gs[g], 1);
  float mean = stats[g * 128 + f] / cnt;
  float ex2  = stats[g * 128 + 64 + f] / cnt;
  float msv = ms[f];
  float var = ex2 - (2.f * msv - msv * msv) * mean * mean;
  meanms[i] = msv * mean;
  scale[i] = rsqrtf(var + GN_EPS) * w[f];
}

// ---------------- GraphNorm, phase C: apply + relu + residual accumulate ----------
__global__ void k_gn_apply(const float* __restrict__ Y, const int* __restrict__ batch,
                           const float* __restrict__ meanms, const float* __restrict__ scale,
                           const float* __restrict__ bias,
                           float* __restrict__ C, float* __restrict__ hsum, int n16, int first){
  int i = blockIdx.x * blockDim.x + threadIdx.x;
  if (i >= n16) return;
  int node = i >> 4, q = i & 15;
  int g = batch[node];
  float4 y = ((const float4*)Y)[i];
  float4 m = ((const float4*)(meanms + g * 64))[q];
  float4 s = ((const float4*)(scale  + g * 64))[q];
  float4 b = ((const float4*)bias)[q];
  float4 v;
  v.x = fmaxf((y.x - m.x) * s.x + b.x, 0.f);
  v.y = fmaxf((y.y - m.y) * s.y + b.y, 0.f);
  v.z = fmaxf((y.z - m.z) * s.z + b.z, 0.f);
  v.w = fmaxf((y.w - m.w) * s.w + b.w, 0.f);
  ((float4*)C)[i] = v;
  if (first){
    ((float4*)hsum)[i] = v;
  } else {
    float4 h = ((float4*)hsum)[i];
    h.x += v.x; h.y += v.y; h.z += v.z; h.w += v.w;
    ((float4*)hsum)[i] = h;
  }
}

// ---------------- pooling pass 1: gate logits, sum h, max h, per-graph gate max ---
__global__ void k_pool1(const float* __restrict__ HS, const int* __restrict__ batch,
                        const float* __restrict__ GW, const float* __restrict__ GB,
                        float* __restrict__ sumbuf, unsigned* __restrict__ maxbuf,
                        float* __restrict__ gatebuf, unsigned* __restrict__ gmaxbuf, int n){
  int wave = (int)((blockIdx.x * blockDim.x + threadIdx.x) >> 6);
  int lane = threadIdx.x & 63;
  int s = wave * GN_NPW;
  if (s >= n) return;
  int e = min(s + GN_NPW, n);
  float gwv = GW[lane];
  float gb = GB[0];
  int cur = batch[s];
  float macc = 0.f, xacc = -INFINITY, gmx = -INFINITY;
  for (int nd = s; nd < e; ++nd){
    int g = batch[nd];
    if (g != cur){
      atomicAdd(&sumbuf[cur * 64 + lane], macc);
      atomicMax(&maxbuf[cur * 64 + lane], fenc(xacc));
      if (lane == 0) atomicMax(&gmaxbuf[cur], fenc(gmx));
      macc = 0.f; xacc = -INFINITY; gmx = -INFINITY; cur = g;
    }
    float hv = HS[(size_t)nd * HDIM + lane];
    macc += hv; xacc = fmaxf(xacc, hv);
    float gv = hv * gwv;
    #pragma unroll
    for (int msk = 1; msk < 64; msk <<= 1) gv += __shfl_xor(gv, msk);
    gv += gb;
    if (lane == 0) gatebuf[nd] = gv;
    gmx = fmaxf(gmx, gv);
  }
  atomicAdd(&sumbuf[cur * 64 + lane], macc);
  atomicMax(&maxbuf[cur * 64 + lane], fenc(xacc));
  if (lane == 0) atomicMax(&gmaxbuf[cur], fenc(gmx));
}

// ---------------- pooling pass 2: softmax numer/denom accumulate ----------------
__global__ void k_pool2(const float* __restrict__ HS, const int* __restrict__ batch,
                        const float* __restrict__ gatebuf, const unsigned* __restrict__ gmaxbuf,
                        float* __restrict__ attbuf, float* __restrict__ denbuf, int n){
  int wave = (int)((blockIdx.x * blockDim.x + threadIdx.x) >> 6);
  int lane = threadIdx.x & 63;
  int s = wave * GN_NPW;
  if (s >= n) return;
  int e = min(s + GN_NPW, n);
  int cur = batch[s];
  float m = fdec(gmaxbuf[cur]);
  float aacc = 0.f, dacc = 0.f;
  for (int nd = s; nd < e; ++nd){
    int g = batch[nd];
    if (g != cur){
      atomicAdd(&attbuf[cur * 64 + lane], aacc);
      if (lane == 0) atomicAdd(&denbuf[cur], dacc);
      aacc = 0.f; dacc = 0.f; cur = g; m = fdec(gmaxbuf[cur]);
    }
    float ex = expf(gatebuf[nd] - m);
    float hv = HS[(size_t)nd * HDIM + lane];
    aacc += ex * hv; dacc += ex;
  }
  atomicAdd(&attbuf[cur * 64 + lane], aacc);
  if (lane == 0) atomicAdd(&denbuf[cur], dacc);
}

// ---------------- pooling pass 3: assemble z and head MLP ----------------
__global__ void k_pool3(const float* __restrict__ attbuf, const float* __restrict__ denbuf,
                        const float* __restrict__ sumbuf, const unsigned* __restrict__ maxbuf,
                        const int* __restrict__ gs, const float* __restrict__ U,
                        const float* __restrict__ HW1, const float* __restrict__ HB1,
                        const float* __restrict__ HW2, const float* __restrict__ HB2,
                        float* __restrict__ out){
  __shared__ float z[200];
  int g = blockIdx.x;
  int tid = threadIdx.x;   // 64 threads
  float cnt = (float)max(gs[g + 1] - gs[g], 1);
  float den = denbuf[g];
  z[tid]       = attbuf[g * 64 + tid] / den;
  z[64 + tid]  = sumbuf[g * 64 + tid] / cnt;
  z[128 + tid] = fdec(maxbuf[g * 64 + tid]);
  if (tid < 3) z[192 + tid] = U[g * 3 + tid];
  __syncthreads();
  float acc = HB1[tid];
  for (int k = 0; k < 195; k++) acc += z[k] * HW1[k * 64 + tid];
  float sv = fmaxf(acc, 0.f) * HW2[tid];
  #pragma unroll
  for (int msk = 1; msk < 64; msk <<= 1) sv += __shfl_xor(sv, msk);
  if (tid == 0) out[g] = sv + HB2[0];
}

extern "C" void kernel_launch(void* const* d_in, const int* in_sizes, int n_in,
                              void* d_out, int out_size, void* d_ws, size_t ws_size,
                              hipStream_t stream){
  const float* x     = (const float*)d_in[0];
  const int*   ei    = (const int*)d_in[1];
  const int*   batch = (const int*)d_in[2];
  const float* u     = (const float*)d_in[3];
  const float* W[3][4]; const float* GNp[3][3];
  for (int l = 0; l < 3; l++){
    int base = 4 + l * 7;
    W[l][0]  = (const float*)d_in[base + 0];
    W[l][1]  = (const float*)d_in[base + 1];
    W[l][2]  = (const float*)d_in[base + 2];
    W[l][3]  = (const float*)d_in[base + 3];
    GNp[l][0]= (const float*)d_in[base + 4];
    GNp[l][1]= (const float*)d_in[base + 5];
    GNp[l][2]= (const float*)d_in[base + 6];
  }
  const float* gate_w = (const float*)d_in[25];
  const float* gate_b = (const float*)d_in[26];
  const float* hw1    = (const float*)d_in[27];
  const float* hb1    = (const float*)d_in[28];
  const float* hw2    = (const float*)d_in[29];
  const float* hb2    = (const float*)d_in[30];
  float* out = (float*)d_out;

  int N = in_sizes[0] / HDIM;
  int E = in_sizes[1] / 2;
  int B = in_sizes[3] / 3;
  const int* src = ei;
  const int* dst = ei + E;

  char* w8 = (char*)d_ws;
  size_t NH = (size_t)N * HDIM * sizeof(float);
  auto alignup = [](size_t v){ return (v + 255) & ~(size_t)255; };
  size_t off = 0;
  float* hsum    = (float*)(w8 + off); off += alignup(NH);
  float* bufA    = (float*)(w8 + off); off += alignup(NH);
  float* bufB    = (float*)(w8 + off); off += alignup(NH);
  float* G       = (float*)(w8 + off); off += alignup(NH);
  float* gatebuf = (float*)(w8 + off); off += alignup((size_t)N * 4);
  int*   deg     = (int*)(w8 + off);   off += alignup((size_t)N * 4);
  int*   offs    = (int*)(w8 + off);   off += alignup((size_t)N * 4);
  int*   cursor  = (int*)(w8 + off);   off += alignup((size_t)N * 4);
  int*   part    = (int*)(w8 + off);   off += alignup(4096);
  int*   csr     = (int*)(w8 + off);   off += alignup((size_t)E * 4);
  float* stats   = (float*)(w8 + off); off += alignup((size_t)B * 128 * 4);
  float* meanms  = (float*)(w8 + off); off += alignup((size_t)B * 64 * 4);
  float* scale   = (float*)(w8 + off); off += alignup((size_t)B * 64 * 4);
  float* sumbuf  = (float*)(w8 + off); off += alignup((size_t)B * 64 * 4);
  unsigned* maxbuf = (unsigned*)(w8 + off); off += alignup((size_t)B * 64 * 4);
  float* attbuf  = (float*)(w8 + off); off += alignup((size_t)B * 64 * 4);
  float* denbuf  = (float*)(w8 + off); off += alignup((size_t)B * 4);
  unsigned* gmaxbuf = (unsigned*)(w8 + off); off += alignup((size_t)B * 4);
  int*   gs      = (int*)(w8 + off);   off += alignup((size_t)(B + 1) * 4);
  (void)ws_size; (void)n_in; (void)out_size;

  hipMemsetAsync(deg, 0, (size_t)N * 4, stream);
  hipMemsetAsync(sumbuf, 0, (size_t)B * 64 * 4, stream);
  hipMemsetAsync(maxbuf, 0, (size_t)B * 64 * 4, stream);   // 0 == fenc(-NaN), below all reals
  hipMemsetAsync(attbuf, 0, (size_t)B * 64 * 4, stream);
  hipMemsetAsync(denbuf, 0, (size_t)B * 4, stream);
  hipMemsetAsync(gmaxbuf, 0, (size_t)B * 4, stream);

  const int tb = 256;
  k_deg<<<(E + tb - 1) / tb, tb, 0, stream>>>(dst, deg, E);
  int nchunk = (N + 1023) / 1024;
  k_scan1<<<nchunk, 256, 0, stream>>>(deg, offs, part, N);
  k_scan2<<<1, 256, 0, stream>>>(part, nchunk);
  k_scan3<<<(N + 255) / 256, 256, 0, stream>>>(offs, cursor, part, N);
  k_scatter<<<(E + tb - 1) / tb, tb, 0, stream>>>(src, dst, cursor, csr, E);
  k_gstart<<<1, 256, 0, stream>>>(batch, N, gs, B);

  int nwaves = (N + GN_NPW - 1) / GN_NPW;
  int segblocks = (nwaves * 64 + tb - 1) / tb;
  int n16 = N * 16;

  const float* P = x;
  float* C = bufA;
  for (int l = 0; l < 3; l++){
    unsigned aggblocks = (unsigned)(((size_t)N * HDIM + 255) / 256);
    k_agg<<<aggblocks, 256, 0, stream>>>(P, csr, offs, deg, G, N);
    k_mlp<<<(N + 127) / 128, 128, 0, stream>>>(G, W[l][0], W[l][1], W[l][2], W[l][3], N);
    hipMemsetAsync(stats, 0, (size_t)B * 128 * 4, stream);
    k_gn_stats<<<segblocks, tb, 0, stream>>>(G, batch, stats, N);
    k_gn_finalize<<<(B * 64 + tb - 1) / tb, tb, 0, stream>>>(stats, gs, GNp[l][0], GNp[l][2],
                                                             meanms, scale, B);
    k_gn_apply<<<(n16 + tb - 1) / tb, tb, 0, stream>>>(G, batch, meanms, scale, GNp[l][1],
                                                       C, hsum, n16, l == 0 ? 1 : 0);
    P = C;
    C = (l == 0) ? bufB : bufA;
  }
  k_pool1<<<segblocks, tb, 0, stream>>>(hsum, batch, gate_w, gate_b,
                                        sumbuf, maxbuf, gatebuf, gmaxbuf, N);
  k_pool2<<<segblocks, tb, 0, stream>>>(hsum, batch, gatebuf, gmaxbuf, attbuf, denbuf, N);
  k_pool3<<<B, 64, 0, stream>>>(attbuf, denbuf, sumbuf, maxbuf, gs, u,
                                hw1, hb1, hw2, hb2, out);
}

// Round 3
// 648.453 us; speedup vs baseline: 1.7829x; 1.1432x over previous
//
#include <hip/hip_runtime.h>
#include <math.h>

#define HDIM 64
#define GN_EPS 1e-5f
#define MAXNB 512          // supports N <= 131072 (bucket = 256 nodes)

__device__ __forceinline__ int lower_bound_i(const int* a, int n, int key){
  int lo = 0, hi = n;
  while (lo < hi){ int mid = (lo + hi) >> 1; if (a[mid] < key) lo = mid + 1; else hi = mid; }
  return lo;
}

// ordered-uint encoding for float atomicMax
__device__ __forceinline__ unsigned fenc(float x){
  unsigned b = __float_as_uint(x);
  return (b & 0x80000000u) ? ~b : (b | 0x80000000u);
}
__device__ __forceinline__ float fdec(unsigned u){
  unsigned b = (u & 0x80000000u) ? (u ^ 0x80000000u) : ~u;
  return __uint_as_float(b);
}

// ---------------- CSR build, pass A: bucket histogram (bucket = dst>>8) ----------
__global__ void k_bhist(const int* __restrict__ dst, int* __restrict__ bcount, int E, int NB){
  __shared__ int lh[MAXNB];
  int tid = threadIdx.x;
  for (int b = tid; b < NB; b += blockDim.x) lh[b] = 0;
  __syncthreads();
  for (int i = blockIdx.x * blockDim.x + tid; i < E; i += gridDim.x * blockDim.x)
    atomicAdd(&lh[dst[i] >> 8], 1);
  __syncthreads();
  for (int b = tid; b < NB; b += blockDim.x){ int c = lh[b]; if (c) atomicAdd(&bcount[b], c); }
}

// ---------------- pass B: scan bucket counts ----------------
__global__ void k_bscan(const int* __restrict__ bcount, int* __restrict__ bbase,
                        int* __restrict__ bcursor, int NB){
  __shared__ int sd[MAXNB];
  int tid = threadIdx.x;   // 512 threads
  int v = (tid < NB) ? bcount[tid] : 0;
  sd[tid] = v; __syncthreads();
  for (int o = 1; o < MAXNB; o <<= 1){
    int t = (tid >= o) ? sd[tid - o] : 0;
    __syncthreads();
    sd[tid] += t;
    __syncthreads();
  }
  int excl = sd[tid] - v;
  if (tid < NB){ bbase[tid] = excl; bcursor[tid] = excl; }
  if (tid == NB - 1) bbase[NB] = excl + v;
}

// ---------------- pass C: reorder edges into bucket-grouped ebuf ----------------
#define RCHUNK 8192
__global__ void k_breorder(const int* __restrict__ src, const int* __restrict__ dst,
                           int* __restrict__ bcursor, int2* __restrict__ ebuf, int E, int NB){
  __shared__ int lh[MAXNB];
  __shared__ int lbase[MAXNB];
  int tid = threadIdx.x;   // 256
  int c0 = blockIdx.x * RCHUNK;
  for (int b = tid; b < NB; b += 256) lh[b] = 0;
  __syncthreads();
  for (int j = 0; j < RCHUNK / 256; j++){
    int i = c0 + j * 256 + tid;
    if (i < E) atomicAdd(&lh[dst[i] >> 8], 1);
  }
  __syncthreads();
  for (int b = tid; b < NB; b += 256){
    int c = lh[b];
    lbase[b] = c ? atomicAdd(&bcursor[b], c) : 0;
    lh[b] = 0;
  }
  __syncthreads();
  for (int j = 0; j < RCHUNK / 256; j++){
    int i = c0 + j * 256 + tid;
    if (i < E){
      int d = dst[i]; int b = d >> 8;
      int r = atomicAdd(&lh[b], 1);
      ebuf[lbase[b] + r] = make_int2(src[i], d);
    }
  }
}

// ---------------- pass D: per-bucket counting sort -> csr/deg/offs ----------------
__global__ void k_bucket_csr(const int2* __restrict__ ebuf, const int* __restrict__ bbase,
                             int* __restrict__ deg, int* __restrict__ offs,
                             int* __restrict__ csr, int N){
  __shared__ int lh[256];
  __shared__ int lsc[256];
  int b = blockIdx.x;
  int lo = b << 8;
  int nn = min(256, N - lo);
  int tid = threadIdx.x;   // 256
  lh[tid] = 0; __syncthreads();
  int es = bbase[b], ee = bbase[b + 1];
  for (int i = es + tid; i < ee; i += 256) atomicAdd(&lh[ebuf[i].y - lo], 1);
  __syncthreads();
  int v = lh[tid];
  lsc[tid] = v; __syncthreads();
  for (int o = 1; o < 256; o <<= 1){
    int t = (tid >= o) ? lsc[tid - o] : 0;
    __syncthreads();
    lsc[tid] += t;
    __syncthreads();
  }
  int excl = lsc[tid] - v;
  if (tid < nn){ deg[lo + tid] = v; offs[lo + tid] = es + excl; }
  __syncthreads();
  lh[tid] = es + excl;     // reuse as cursor
  __syncthreads();
  for (int i = es + tid; i < ee; i += 256){
    int2 e = ebuf[i];
    int pos = atomicAdd(&lh[e.y - lo], 1);
    csr[pos] = e.x;
  }
}

// graph start offsets (batch is sorted)
__global__ void k_gstart(const int* __restrict__ batch, int n, int* __restrict__ gs, int B){
  int g = blockIdx.x * blockDim.x + threadIdx.x;
  if (g <= B) gs[g] = lower_bound_i(batch, n, g);
}

// ---------------- GIN aggregation: G[n] = P[n] + sum_{e->n} P[src] ----------------
__global__ void k_agg(const float* __restrict__ P, const int* __restrict__ csr,
                      const int* __restrict__ offs, const int* __restrict__ deg,
                      float* __restrict__ G, int n){
  int gi = blockIdx.x * blockDim.x + threadIdx.x;
  int node = gi >> 6;
  int lane = gi & 63;
  if (node >= n) return;
  int st = offs[node], cnt = deg[node];
  float self = P[(size_t)node * HDIM + lane];
  float a0 = 0.f, a1 = 0.f, a2 = 0.f, a3 = 0.f;
  for (int base = 0; base < cnt; base += 64){
    int rem = cnt - base;
    int s = (lane < rem) ? csr[st + base + lane] : 0;
    int m = min(rem, 64);
    int j = 0;
    for (; j + 4 <= m; j += 4){
      int s0 = __shfl(s, j), s1 = __shfl(s, j + 1), s2 = __shfl(s, j + 2), s3 = __shfl(s, j + 3);
      a0 += P[(size_t)s0 * HDIM + lane];
      a1 += P[(size_t)s1 * HDIM + lane];
      a2 += P[(size_t)s2 * HDIM + lane];
      a3 += P[(size_t)s3 * HDIM + lane];
    }
    for (; j < m; ++j){ int sj = __shfl(s, j); a0 += P[(size_t)sj * HDIM + lane]; }
  }
  G[(size_t)node * HDIM + lane] = self + ((a0 + a1) + (a2 + a3));
}

// ---------------- GIN MLP: G[n] = relu(G[n] @ W1 + B1) @ W2 + B2 (in place) -------
__global__ __launch_bounds__(128, 2) void k_mlp(float* __restrict__ G,
    const float* __restrict__ W1, const float* __restrict__ B1,
    const float* __restrict__ W2, const float* __restrict__ B2, int n){
  __shared__ float lt[64 * 128];
  int tid = threadIdx.x;
  int node = blockIdx.x * 128 + tid;
  bool ok = node < n;
  const float4* hp = (const float4*)(G + (ok ? (size_t)node * HDIM : 0));

  float t[64];
  #pragma unroll
  for (int j = 0; j < 64; j++) t[j] = B1[j];
  for (int ii = 0; ii < 4; ++ii){
    float4 c0 = hp[ii * 4 + 0], c1 = hp[ii * 4 + 1], c2 = hp[ii * 4 + 2], c3 = hp[ii * 4 + 3];
    float hc[16] = {c0.x, c0.y, c0.z, c0.w, c1.x, c1.y, c1.z, c1.w,
                    c2.x, c2.y, c2.z, c2.w, c3.x, c3.y, c3.z, c3.w};
    const float* wrow = W1 + (size_t)ii * 16 * 64;
    #pragma unroll
    for (int k = 0; k < 16; k++){
      float hv = hc[k];
      #pragma unroll
      for (int j = 0; j < 64; j++) t[j] += hv * wrow[k * 64 + j];
    }
  }
  #pragma unroll
  for (int j = 0; j < 64; j++) lt[j * 128 + tid] = fmaxf(t[j], 0.f);

  float o[64];
  #pragma unroll
  for (int j = 0; j < 64; j++) o[j] = B2[j];
  for (int ii = 0; ii < 4; ++ii){
    const float* wrow = W2 + (size_t)ii * 16 * 64;
    #pragma unroll
    for (int k = 0; k < 16; k++){
      float tv = lt[(ii * 16 + k) * 128 + tid];
      #pragma unroll
      for (int j = 0; j < 64; j++) o[j] += tv * wrow[k * 64 + j];
    }
  }
  if (ok){
    float4* op = (float4*)(G + (size_t)node * HDIM);
    #pragma unroll
    for (int q = 0; q < 16; q++) op[q] = make_float4(o[q*4], o[q*4+1], o[q*4+2], o[q*4+3]);
  }
}

// ---------------- GraphNorm, phase A: per-graph sum / sumsq (chunked-flush) -------
#define GN_NPW 32
__global__ void k_gn_stats(const float* __restrict__ Y, const int* __restrict__ batch,
                           float* __restrict__ stats /*[B][2][64]*/, int n){
  int wave = (int)((blockIdx.x * blockDim.x + threadIdx.x) >> 6);
  int lane = threadIdx.x & 63;
  int s = wave * GN_NPW;
  if (s >= n) return;
  int e = min(s + GN_NPW, n);
  int cur = batch[s];
  float a = 0.f, a2 = 0.f;
  for (int nd = s; nd < e; ++nd){
    int g = batch[nd];
    if (g != cur){
      atomicAdd(&stats[cur * 128 + lane], a);
      atomicAdd(&stats[cur * 128 + 64 + lane], a2);
      a = 0.f; a2 = 0.f; cur = g;
    }
    float v = Y[(size_t)nd * HDIM + lane];
    a += v; a2 += v * v;
  }
  atomicAdd(&stats[cur * 128 + lane], a);
  atomicAdd(&stats[cur * 128 + 64 + lane], a2);
}

// ---------------- GraphNorm, phase B: finalize mean*ms and scale ----------------
__global__ void k_gn_finalize(const float* __restrict__ stats, const int* __restrict__ gs,
                              const float* __restrict__ w, const float* __restrict__ ms,
                              float* __restrict__ meanms, float* __restrict__ scale, int B){
  int i = blockIdx.x * blockDim.x + threadIdx.x;
  if (i >= B * 64) return;
  int g = i >> 6, f = i & 63;
  float cnt = (float)max(gs[g + 1] - gs[g], 1);
  float mean = stats[g * 128 + f] / cnt;
  float ex2  = stats[g * 128 + 64 + f] / cnt;
  float msv = ms[f];
  float var = ex2 - (2.f * msv - msv * msv) * mean * mean;
  meanms[i] = msv * mean;
  scale[i] = rsqrtf(var + GN_EPS) * w[f];
}

// ---------------- GraphNorm, phase C: apply + relu + residual accumulate ----------
__global__ void k_gn_apply(const float* __restrict__ Y, const int* __restrict__ batch,
                           const float* __restrict__ meanms, const float* __restrict__ scale,
                           const float* __restrict__ bias,
                           float* __restrict__ C, float* __restrict__ hsum, int n16,
                           int first, int writeC){
  int i = blockIdx.x * blockDim.x + threadIdx.x;
  if (i >= n16) return;
  int node = i >> 4, q = i & 15;
  int g = batch[node];
  float4 y = ((const float4*)Y)[i];
  float4 m = ((const float4*)(meanms + g * 64))[q];
  float4 s = ((const float4*)(scale  + g * 64))[q];
  float4 b = ((const float4*)bias)[q];
  float4 v;
  v.x = fmaxf((y.x - m.x) * s.x + b.x, 0.f);
  v.y = fmaxf((y.y - m.y) * s.y + b.y, 0.f);
  v.z = fmaxf((y.z - m.z) * s.z + b.z, 0.f);
  v.w = fmaxf((y.w - m.w) * s.w + b.w, 0.f);
  if (writeC) ((float4*)C)[i] = v;
  if (first){
    ((float4*)hsum)[i] = v;
  } else {
    float4 h = ((float4*)hsum)[i];
    h.x += v.x; h.y += v.y; h.z += v.z; h.w += v.w;
    ((float4*)hsum)[i] = h;
  }
}

// ---------------- pooling pass 1 ----------------
__global__ void k_pool1(const float* __restrict__ HS, const int* __restrict__ batch,
                        const float* __restrict__ GW, const float* __restrict__ GB,
                        float* __restrict__ sumbuf, unsigned* __restrict__ maxbuf,
                        float* __restrict__ gatebuf, unsigned* __restrict__ gmaxbuf, int n){
  int wave = (int)((blockIdx.x * blockDim.x + threadIdx.x) >> 6);
  int lane = threadIdx.x & 63;
  int s = wave * GN_NPW;
  if (s >= n) return;
  int e = min(s + GN_NPW, n);
  float gwv = GW[lane];
  float gb = GB[0];
  int cur = batch[s];
  float macc = 0.f, xacc = -INFINITY, gmx = -INFINITY;
  for (int nd = s; nd < e; ++nd){
    int g = batch[nd];
    if (g != cur){
      atomicAdd(&sumbuf[cur * 64 + lane], macc);
      atomicMax(&maxbuf[cur * 64 + lane], fenc(xacc));
      if (lane == 0) atomicMax(&gmaxbuf[cur], fenc(gmx));
      macc = 0.f; xacc = -INFINITY; gmx = -INFINITY; cur = g;
    }
    float hv = HS[(size_t)nd * HDIM + lane];
    macc += hv; xacc = fmaxf(xacc, hv);
    float gv = hv * gwv;
    #pragma unroll
    for (int msk = 1; msk < 64; msk <<= 1) gv += __shfl_xor(gv, msk);
    gv += gb;
    if (lane == 0) gatebuf[nd] = gv;
    gmx = fmaxf(gmx, gv);
  }
  atomicAdd(&sumbuf[cur * 64 + lane], macc);
  atomicMax(&maxbuf[cur * 64 + lane], fenc(xacc));
  if (lane == 0) atomicMax(&gmaxbuf[cur], fenc(gmx));
}

// ---------------- pooling pass 2 ----------------
__global__ void k_pool2(const float* __restrict__ HS, const int* __restrict__ batch,
                        const float* __restrict__ gatebuf, const unsigned* __restrict__ gmaxbuf,
                        float* __restrict__ attbuf, float* __restrict__ denbuf, int n){
  int wave = (int)((blockIdx.x * blockDim.x + threadIdx.x) >> 6);
  int lane = threadIdx.x & 63;
  int s = wave * GN_NPW;
  if (s >= n) return;
  int e = min(s + GN_NPW, n);
  int cur = batch[s];
  float m = fdec(gmaxbuf[cur]);
  float aacc = 0.f, dacc = 0.f;
  for (int nd = s; nd < e; ++nd){
    int g = batch[nd];
    if (g != cur){
      atomicAdd(&attbuf[cur * 64 + lane], aacc);
      if (lane == 0) atomicAdd(&denbuf[cur], dacc);
      aacc = 0.f; dacc = 0.f; cur = g; m = fdec(gmaxbuf[cur]);
    }
    float ex = expf(gatebuf[nd] - m);
    float hv = HS[(size_t)nd * HDIM + lane];
    aacc += ex * hv; dacc += ex;
  }
  atomicAdd(&attbuf[cur * 64 + lane], aacc);
  if (lane == 0) atomicAdd(&denbuf[cur], dacc);
}

// ---------------- pooling pass 3 ----------------
__global__ void k_pool3(const float* __restrict__ attbuf, const float* __restrict__ denbuf,
                        const float* __restrict__ sumbuf, const unsigned* __restrict__ maxbuf,
                        const int* __restrict__ gs, const float* __restrict__ U,
                        const float* __restrict__ HW1, const float* __restrict__ HB1,
                        const float* __restrict__ HW2, const float* __restrict__ HB2,
                        float* __restrict__ out){
  __shared__ float z[200];
  int g = blockIdx.x;
  int tid = threadIdx.x;   // 64 threads
  float cnt = (float)max(gs[g + 1] - gs[g], 1);
  float den = denbuf[g];
  z[tid]       = attbuf[g * 64 + tid] / den;
  z[64 + tid]  = sumbuf[g * 64 + tid] / cnt;
  z[128 + tid] = fdec(maxbuf[g * 64 + tid]);
  if (tid < 3) z[192 + tid] = U[g * 3 + tid];
  __syncthreads();
  float acc = HB1[tid];
  for (int k = 0; k < 195; k++) acc += z[k] * HW1[k * 64 + tid];
  float sv = fmaxf(acc, 0.f) * HW2[tid];
  #pragma unroll
  for (int msk = 1; msk < 64; msk <<= 1) sv += __shfl_xor(sv, msk);
  if (tid == 0) out[g] = sv + HB2[0];
}

extern "C" void kernel_launch(void* const* d_in, const int* in_sizes, int n_in,
                              void* d_out, int out_size, void* d_ws, size_t ws_size,
                              hipStream_t stream){
  const float* x     = (const float*)d_in[0];
  const int*   ei    = (const int*)d_in[1];
  const int*   batch = (const int*)d_in[2];
  const float* u     = (const float*)d_in[3];
  const float* W[3][4]; const float* GNp[3][3];
  for (int l = 0; l < 3; l++){
    int base = 4 + l * 7;
    W[l][0]  = (const float*)d_in[base + 0];
    W[l][1]  = (const float*)d_in[base + 1];
    W[l][2]  = (const float*)d_in[base + 2];
    W[l][3]  = (const float*)d_in[base + 3];
    GNp[l][0]= (const float*)d_in[base + 4];
    GNp[l][1]= (const float*)d_in[base + 5];
    GNp[l][2]= (const float*)d_in[base + 6];
  }
  const float* gate_w = (const float*)d_in[25];
  const float* gate_b = (const float*)d_in[26];
  const float* hw1    = (const float*)d_in[27];
  const float* hb1    = (const float*)d_in[28];
  const float* hw2    = (const float*)d_in[29];
  const float* hb2    = (const float*)d_in[30];
  float* out = (float*)d_out;

  int N = in_sizes[0] / HDIM;
  int E = in_sizes[1] / 2;
  int B = in_sizes[3] / 3;
  const int* src = ei;
  const int* dst = ei + E;
  int NB = (N + 255) >> 8;     // <= MAXNB for N <= 131072

  char* w8 = (char*)d_ws;
  size_t NH = (size_t)N * HDIM * sizeof(float);
  auto alignup = [](size_t v){ return (v + 255) & ~(size_t)255; };
  size_t off = 0;
  float* hsum    = (float*)(w8 + off); off += alignup(NH);
  float* bufA    = (float*)(w8 + off); off += alignup(NH);
  float* bufB    = (float*)(w8 + off); off += alignup(NH);
  float* G       = (float*)(w8 + off); off += alignup(NH);
  float* gatebuf = (float*)(w8 + off); off += alignup((size_t)N * 4);
  int*   deg     = (int*)(w8 + off);   off += alignup((size_t)N * 4);
  int*   offs    = (int*)(w8 + off);   off += alignup((size_t)N * 4);
  int*   csr     = (int*)(w8 + off);   off += alignup((size_t)E * 4);
  int2*  ebuf    = (int2*)(w8 + off);  off += alignup((size_t)E * 8);
  int*   bcount  = (int*)(w8 + off);   off += alignup((size_t)(MAXNB + 1) * 4);
  int*   bbase   = (int*)(w8 + off);   off += alignup((size_t)(MAXNB + 1) * 4);
  int*   bcursor = (int*)(w8 + off);   off += alignup((size_t)(MAXNB + 1) * 4);
  float* stats   = (float*)(w8 + off); off += alignup((size_t)B * 128 * 4);
  float* meanms  = (float*)(w8 + off); off += alignup((size_t)B * 64 * 4);
  float* scale   = (float*)(w8 + off); off += alignup((size_t)B * 64 * 4);
  float* sumbuf  = (float*)(w8 + off); off += alignup((size_t)B * 64 * 4);
  unsigned* maxbuf = (unsigned*)(w8 + off); off += alignup((size_t)B * 64 * 4);
  float* attbuf  = (float*)(w8 + off); off += alignup((size_t)B * 64 * 4);
  float* denbuf  = (float*)(w8 + off); off += alignup((size_t)B * 4);
  unsigned* gmaxbuf = (unsigned*)(w8 + off); off += alignup((size_t)B * 4);
  int*   gs      = (int*)(w8 + off);   off += alignup((size_t)(B + 1) * 4);
  (void)ws_size; (void)n_in; (void)out_size;

  hipMemsetAsync(bcount, 0, (size_t)(MAXNB + 1) * 4, stream);
  hipMemsetAsync(sumbuf, 0, (size_t)B * 64 * 4, stream);
  hipMemsetAsync(maxbuf, 0, (size_t)B * 64 * 4, stream);   // 0 == below all reals in fenc order
  hipMemsetAsync(attbuf, 0, (size_t)B * 64 * 4, stream);
  hipMemsetAsync(denbuf, 0, (size_t)B * 4, stream);
  hipMemsetAsync(gmaxbuf, 0, (size_t)B * 4, stream);

  const int tb = 256;
  k_bhist<<<256, tb, 0, stream>>>(dst, bcount, E, NB);
  k_bscan<<<1, MAXNB, 0, stream>>>(bcount, bbase, bcursor, NB);
  k_breorder<<<(E + RCHUNK - 1) / RCHUNK, tb, 0, stream>>>(src, dst, bcursor, ebuf, E, NB);
  k_bucket_csr<<<NB, tb, 0, stream>>>(ebuf, bbase, deg, offs, csr, N);
  k_gstart<<<1, 256, 0, stream>>>(batch, N, gs, B);

  int nwaves = (N + GN_NPW - 1) / GN_NPW;
  int segblocks = (nwaves * 64 + tb - 1) / tb;
  int n16 = N * 16;

  const float* P = x;
  float* C = bufA;
  for (int l = 0; l < 3; l++){
    unsigned aggblocks = (unsigned)(((size_t)N * HDIM + 255) / 256);
    k_agg<<<aggblocks, 256, 0, stream>>>(P, csr, offs, deg, G, N);
    k_mlp<<<(N + 127) / 128, 128, 0, stream>>>(G, W[l][0], W[l][1], W[l][2], W[l][3], N);
    hipMemsetAsync(stats, 0, (size_t)B * 128 * 4, stream);
    k_gn_stats<<<segblocks, tb, 0, stream>>>(G, batch, stats, N);
    k_gn_finalize<<<(B * 64 + tb - 1) / tb, tb, 0, stream>>>(stats, gs, GNp[l][0], GNp[l][2],
                                                             meanms, scale, B);
    k_gn_apply<<<(n16 + tb - 1) / tb, tb, 0, stream>>>(G, batch, meanms, scale, GNp[l][1],
                                                       C, hsum, n16, l == 0 ? 1 : 0,
                                                       l == 2 ? 0 : 1);
    P = C;
    C = (l == 0) ? bufB : bufA;
  }
  k_pool1<<<segblocks, tb, 0, stream>>>(hsum, batch, gate_w, gate_b,
                                        sumbuf, maxbuf, gatebuf, gmaxbuf, N);
  k_pool2<<<segblocks, tb, 0, stream>>>(hsum, batch, gatebuf, gmaxbuf, attbuf, denbuf, N);
  k_pool3<<<B, 64, 0, stream>>>(attbuf, denbuf, sumbuf, maxbuf, gs, u,
                                hw1, hb1, hw2, hb2, out);
}